// Round 12
// baseline (2765.716 us; speedup 1.0000x reference)
//
#include <hip/hip_runtime.h>

typedef unsigned short u16;
typedef unsigned int u32;
typedef unsigned long long u64;

typedef short bf16x8 __attribute__((ext_vector_type(8)));
typedef float f32x4 __attribute__((ext_vector_type(4)));
typedef u32 u32x4 __attribute__((ext_vector_type(4)));

#define NB 64
#define NS 512
#define ND 768
#define NH 384
#define NT_OUT 22
#define S2 272           // materialized xg time extent (n[b] <= 256 < 272)
#define NG 1536          // 4*H
#define MGEMM (NB*S2)    // 17408
#define MAGIC 0x5A5AA5A5u
#define MAX_RETRY 1000000  // watchdog: visibility failure -> wrong answer, never a hang
#define NQC 6              // j-chunks per cluster (64 j each)

__device__ __forceinline__ u16 f2b(float f) {
    u32 u = __float_as_uint(f);
    u32 r = (u + 0x7fffu + ((u >> 16) & 1u)) >> 16;
    return (u16)r;
}
__device__ __forceinline__ float b2f(u16 s) { return __uint_as_float(((u32)s) << 16); }

__device__ __forceinline__ float sigm(float x) {
    return __builtin_amdgcn_rcpf(1.f + __expf(-x));
}
__device__ __forceinline__ float tanh_(float x) {
    return 1.f - 2.f * __builtin_amdgcn_rcpf(1.f + __expf(2.f * x));
}

__device__ __forceinline__ void gl_lds16(const void* g, void* l) {
    __builtin_amdgcn_global_load_lds(
        (const __attribute__((address_space(1))) unsigned int*)g,
        (__attribute__((address_space(3))) unsigned int*)l, 16, 0, 0);
}

// ---------------- exchange access helpers ----------------
// HW LESSON (R2 vs R4 A/B): plain global_load with sc0/sc1 can hit a STALE L1 line
// on gfx950. `nt` (no L1 allocate) makes re-loads observe fresh L2 data.
// vmcnt LESSON (R9): vmcnt completes IN ORDER; retry loads are the NEWEST ops and
// are only guaranteed complete at vmcnt(0) -> polls must run with an L2-only queue
// in front of them. ci loads are issued NEWER than the exchange loads (R12) so
// counted poll waits never touch them.
__device__ __forceinline__ u32 ld_sc0(const int* p) {
    u32 v;
    asm volatile("global_load_dword %0, %1, off sc0 nt\n\t"
                 "s_waitcnt vmcnt(0)"
                 : "=&v"(v) : "v"(p) : "memory");
    return v;
}
__device__ __forceinline__ void st_sc0(int* p, u32 v) {
    asm volatile("global_store_dword %0, %1, off sc0" :: "v"(p), "v"(v) : "memory");
}

// one chunk (64 j = 2 k-slices): 4x dwordx4 of tagged words, no wait
__device__ __forceinline__ void ld4_fast_nw(const u32* p,
        u32x4& A, u32x4& B, u32x4& C, u32x4& D) {
    asm volatile(
        "global_load_dwordx4 %0, %4, off sc0 nt\n\t"
        "global_load_dwordx4 %1, %4, off offset:16 sc0 nt\n\t"
        "global_load_dwordx4 %2, %4, off offset:128 sc0 nt\n\t"
        "global_load_dwordx4 %3, %4, off offset:144 sc0 nt"
        : "=&v"(A), "=&v"(B), "=&v"(C), "=&v"(D)
        : "v"(p) : "memory");
}
__device__ __forceinline__ void ld4_fast_wt(const u32* p,
        u32x4& A, u32x4& B, u32x4& C, u32x4& D) {
    asm volatile(
        "global_load_dwordx4 %0, %4, off sc0 nt\n\t"
        "global_load_dwordx4 %1, %4, off offset:16 sc0 nt\n\t"
        "global_load_dwordx4 %2, %4, off offset:128 sc0 nt\n\t"
        "global_load_dwordx4 %3, %4, off offset:144 sc0 nt\n\t"
        "s_waitcnt vmcnt(0)"
        : "=&v"(A), "=&v"(B), "=&v"(C), "=&v"(D)
        : "v"(p) : "memory");
}
__device__ __forceinline__ void ld4_slow(const u32* p,
        u32x4& A, u32x4& B, u32x4& C, u32x4& D) {
    #pragma unroll
    for (int e = 0; e < 4; e++) {
        A[e] = __hip_atomic_load(p + e,      __ATOMIC_RELAXED, __HIP_MEMORY_SCOPE_AGENT);
        B[e] = __hip_atomic_load(p + 4 + e,  __ATOMIC_RELAXED, __HIP_MEMORY_SCOPE_AGENT);
        C[e] = __hip_atomic_load(p + 32 + e, __ATOMIC_RELAXED, __HIP_MEMORY_SCOPE_AGENT);
        D[e] = __hip_atomic_load(p + 36 + e, __ATOMIC_RELAXED, __HIP_MEMORY_SCOPE_AGENT);
    }
}
__device__ __forceinline__ void ld4_nw(bool fast, const u32* p,
        u32x4& A, u32x4& B, u32x4& C, u32x4& D) {
    if (fast) ld4_fast_nw(p, A, B, C, D);
    else      ld4_slow(p, A, B, C, D);
}
__device__ __forceinline__ void ld4_wt(bool fast, const u32* p,
        u32x4& A, u32x4& B, u32x4& C, u32x4& D) {
    if (fast) ld4_fast_wt(p, A, B, C, D);
    else      ld4_slow(p, A, B, C, D);
}
#define WAIT_VM(N) do { __builtin_amdgcn_sched_barrier(0); \
    asm volatile("s_waitcnt vmcnt(" #N ")" ::: "memory"); \
    __builtin_amdgcn_sched_barrier(0); } while (0)
// LDS-only barrier (global exchange is self-validating; no vm drain)
__device__ __forceinline__ void ldsbar() {
    asm volatile("s_waitcnt lgkmcnt(0)" ::: "memory");
    __builtin_amdgcn_s_barrier();
    __builtin_amdgcn_sched_barrier(0);
}

// sum of low-16 tags of 16 words; tags monotone (stale in {0, T-4}) so
// sum == 16*T  <=>  all 16 words carry tag T.
__device__ __forceinline__ u32 sum4(const u32x4& a, const u32x4& b,
                                    const u32x4& c, const u32x4& d) {
    u32 s = (a[0] & 0xffffu) + (a[1] & 0xffffu) + (a[2] & 0xffffu) + (a[3] & 0xffffu);
    s += (b[0] & 0xffffu) + (b[1] & 0xffffu) + (b[2] & 0xffffu) + (b[3] & 0xffffu);
    s += (c[0] & 0xffffu) + (c[1] & 0xffffu) + (c[2] & 0xffffu) + (c[3] & 0xffffu);
    s += (d[0] & 0xffffu) + (d[1] & 0xffffu) + (d[2] & 0xffffu) + (d[3] & 0xffffu);
    return s;
}
// pack 8 tagged words (h in high 16 bits) -> bf16x8 fragment
__device__ __forceinline__ bf16x8 packf(const u32x4& lo, const u32x4& hi) {
    union { u32 q[4]; bf16x8 v; } U;
    U.q[0] = __builtin_amdgcn_perm(lo[1], lo[0], 0x07060302u);
    U.q[1] = __builtin_amdgcn_perm(lo[3], lo[2], 0x07060302u);
    U.q[2] = __builtin_amdgcn_perm(hi[1], hi[0], 0x07060302u);
    U.q[3] = __builtin_amdgcn_perm(hi[3], hi[2], 0x07060302u);
    return U.v;
}

// ---------------- prep: align/gather -> embeds bf16 [64][272][768] ----------------
__global__ void k_prep(const float* __restrict__ hidden, const int* __restrict__ start_ids,
                       const int* __restrict__ masks, u16* __restrict__ embeds) {
    int b = blockIdx.x >> 2;
    int quarter = blockIdx.x & 3;
    int tid = threadIdx.x;
    __shared__ int red[256];
    int cn = 0, cm = 0;
    for (int s = tid; s < NS; s += 256) {
        cn += (start_ids[b * NS + s] >= 0) ? 1 : 0;
        cm += (masks[b * NS + s] != 0) ? 1 : 0;
    }
    red[tid] = cn + (cm << 16);
    __syncthreads();
    #pragma unroll
    for (int off = 128; off > 0; off >>= 1) {
        if (tid < off) red[tid] += red[tid + off];
        __syncthreads();
    }
    int n = red[0] & 0xffff;
    int slen = red[0] >> 16;
    n = min(max(n, 1), NS);
    int last = start_ids[b * NS + n - 1];
    for (int t = quarter * 68; t < quarter * 68 + 68; ++t) {
        int idx;
        if (t == 0) idx = 0;
        else if (t < n) idx = start_ids[b * NS + t] - 1;
        else if (t == n) idx = last;
        else idx = 0;
        idx = min(max(idx, 0), NS - 1);
        bool keep = t < slen;
        const float* src = hidden + ((size_t)b * NS + idx) * ND;
        u16* dst = embeds + ((size_t)b * S2 + t) * ND;
        if (tid < 192) {
            float4 v = keep ? *(const float4*)(src + tid * 4) : make_float4(0.f, 0.f, 0.f, 0.f);
            union { u16 u[4]; uint2 q; } pk;
            pk.u[0] = f2b(v.x); pk.u[1] = f2b(v.y); pk.u[2] = f2b(v.z); pk.u[3] = f2b(v.w);
            *(uint2*)(dst + tid * 4) = pk.q;
        }
    }
}

// ---------------- weights: cast W_ih (cat) to bf16, bias sums, h0 cast ----------------
__global__ void k_weights(const float* __restrict__ wf, const float* __restrict__ wb,
                          const float* __restrict__ bihf, const float* __restrict__ bhhf,
                          const float* __restrict__ bihb, const float* __restrict__ bhhb,
                          const float* __restrict__ h0,
                          u16* __restrict__ wihcat, float* __restrict__ biascat,
                          u16* __restrict__ h0buf) {
    int i0 = blockIdx.x * blockDim.x + threadIdx.x;
    int NTH = gridDim.x * blockDim.x;
    for (size_t i = i0; i < (size_t)2 * NG * ND; i += NTH) {
        size_t nrow = i / ND, k = i - nrow * ND;
        float v = (nrow < NG) ? wf[nrow * ND + k] : wb[(nrow - NG) * ND + k];
        wihcat[i] = f2b(v);
    }
    for (int i = i0; i < 2 * NG; i += NTH)
        biascat[i] = (i < NG) ? bihf[i] + bhhf[i] : bihb[i - NG] + bhhb[i - NG];
    for (int i = i0; i < 2 * NB * NH; i += NTH) h0buf[i] = f2b(h0[i]);
}

// ---------------- pack Whh into MFMA B-fragment order (GATE-LOCAL) ----------------
// layout: [d][qc6][wj4][gate4][ks12][lane][8]
__global__ void k_packwhh(const float* __restrict__ whhf, const float* __restrict__ whhb,
                          u16* __restrict__ pack) {
    int ft = blockIdx.x * 256 + threadIdx.x;
    if (ft >= 2 * NQC * 4 * 4 * 12 * 64) return;
    int lane = ft & 63;
    int grp = ft >> 6;
    int ks = grp % 12; grp /= 12;
    int gate = grp & 3; grp >>= 2;
    int wj = grp & 3;  grp >>= 2;
    int qc = grp % NQC;
    int d  = grp / NQC;
    const float* W = d ? whhb : whhf;
    int col = gate * NH + qc * 64 + wj * 16 + (lane & 15);
    int k0 = ks * 32 + (lane >> 4) * 8;
    u16* dst = pack + (size_t)ft * 8;
    #pragma unroll
    for (int e = 0; e < 8; e++) dst[e] = f2b(W[(size_t)col * NH + k0 + e]);
}

// ---------------- GEMM: xg[d][b][t<272][1536] (bf16) = embeds @ WihcatT + bias ----------------
__launch_bounds__(256, 2)
__global__ void k_gemm(const u16* __restrict__ A, const u16* __restrict__ Bw,
                       const float* __restrict__ biascat, u16* __restrict__ xg) {
    __shared__ u16 As[128 * 32];
    __shared__ u16 Bs[128 * 32];
    int tid = threadIdx.x;
    int lane = tid & 63, wid = tid >> 6;
    int l15 = lane & 15, q4 = lane >> 4;
    int bn = blockIdx.x;   // 24 tiles of N=3072
    int bm = blockIdx.y;   // 136 tiles of M=17408
    int wm = (wid >> 1) * 64, wn = (wid & 1) * 64;
    f32x4 acc[4][4] = {};
    for (int k0 = 0; k0 < ND; k0 += 32) {
        #pragma unroll
        for (int j = 0; j < 2; j++) {
            int fl = tid + j * 256;
            int row = fl >> 2, cb = fl & 3;
            const u16* ga = A + (size_t)(bm * 128 + row) * ND + k0 + cb * 8;
            gl_lds16(ga, &As[(size_t)(wid * 64 + j * 256) * 8]);
            const u16* gb = Bw + (size_t)(bn * 128 + row) * ND + k0 + cb * 8;
            gl_lds16(gb, &Bs[(size_t)(wid * 64 + j * 256) * 8]);
        }
        __syncthreads();
        bf16x8 af[4], bf[4];
        #pragma unroll
        for (int mt = 0; mt < 4; mt++)
            af[mt] = *(const bf16x8*)&As[(wm + mt * 16 + l15) * 32 + q4 * 8];
        #pragma unroll
        for (int nt = 0; nt < 4; nt++)
            bf[nt] = *(const bf16x8*)&Bs[(wn + nt * 16 + l15) * 32 + q4 * 8];
        #pragma unroll
        for (int mt = 0; mt < 4; mt++)
            #pragma unroll
            for (int nt = 0; nt < 4; nt++)
                acc[mt][nt] = __builtin_amdgcn_mfma_f32_16x16x32_bf16(af[mt], bf[nt], acc[mt][nt], 0, 0, 0);
        __syncthreads();
    }
    #pragma unroll
    for (int nt = 0; nt < 4; nt++) {
        int gn = bn * 128 + wn + nt * 16 + l15;
        int d = gn >= NG ? 1 : 0;
        int col = gn - d * NG;
        float bias = biascat[gn];
        #pragma unroll
        for (int mt = 0; mt < 4; mt++) {
            #pragma unroll
            for (int r = 0; r < 4; r++) {
                int m = bm * 128 + wm + mt * 16 + q4 * 4 + r;
                int b = m / S2, t = m - b * S2;
                float v = acc[mt][nt][r] + bias;
                xg[((size_t)(d * NB + b) * S2 + t) * NG + col] = f2b(v);
            }
        }
    }
}

// ---------------- recurrence: R11 + 2-deep ci pipeline ----------------
// 48 WGs; cluster = (dir, batch-group) of SIX 64-j WGs (blk%8 -> same-XCD heuristic).
// R12 change: ci(t+1) is issued at step START, right after the 20 exchange loads.
// Queue order: [stores(8)|ci(t)] [exch(20)] [ci(t+1)(16)].
//  - WAIT(36) at entry drains stores+ci(t); ci(t) has been in flight a FULL STEP
//    (~2900cy >> L3 latency) -> the old ~300cy L3 entry-wait disappears.
//  - polls (counted 32/28/24/20/16) drain only exchange loads; ci(t+1) is NEWER
//    so it never blocks them (R9 in-order rule respected).
//  - retries end vmcnt(0) (may touch ci(t+1), >=500cy elapsed -> small residual).
//  - cr double-buffered as NAMED arrays with unroll-by-2 (rule: no runtime-indexed
//    register arrays -> scratch).
__launch_bounds__(256, 1)
__global__ void k_recur(const u16* __restrict__ whhpack, const u16* __restrict__ xg,
                        const float* __restrict__ biascat, const u16* __restrict__ h0buf,
                        const float* __restrict__ c0, u16* __restrict__ hout,
                        int* __restrict__ flags, u32* __restrict__ xch) {
    const int blk = blockIdx.x;      // 0..47
    const int qc = blk >> 3;         // j-chunk 0..5
    const int cl = blk & 7;          // cluster id
    const int d = cl >> 2;           // direction
    const int g = cl & 3;            // batch group (16 batches)
    const int tid = threadIdx.x, lane = tid & 63, w = tid >> 6;  // w = 16-j tile
    const int q4 = lane >> 4, l15 = lane & 15;

    __shared__ u16 hlds[2][16 * 72];   // own 64-j chunk, double-buffered, pad 72
    __shared__ int s_fast;

    // stationary Whh B-fragments: bfr[gate][j], j=2i+(0|1) = (lo|hi) 32-k slice of
    // chunk (qc+i)%6 (i=0 own).
    bf16x8 bfr[4][12];
    #pragma unroll
    for (int gg = 0; gg < 4; gg++)
        #pragma unroll
        for (int j = 0; j < 12; j++) {
            int ksg = 2 * ((qc + (j >> 1)) % NQC) + (j & 1);
            bfr[gg][j] = *(const bf16x8*)(whhpack +
                ((size_t)((((d * NQC + qc) * 4 + w) * 4 + gg) * 12 + ksg) * 64 + lane) * 8);
        }

    // c-state: thread owns (batch=q4*4+r, j=w*16+l15), r=0..3
    float cre[4];
    #pragma unroll
    for (int r = 0; r < 4; r++)
        cre[r] = c0[(size_t)(d * NB + g * 16 + q4 * 4 + r) * NH + qc * 64 + w * 16 + l15];
    float biasreg[4];
    #pragma unroll
    for (int gg = 0; gg < 4; gg++)
        biasreg[gg] = biascat[d * NG + gg * NH + qc * 64 + w * 16 + l15];

    // ---- co-location probe + consensus (once per launch) ----
    if (tid == 0) {
        int* pzb = flags + cl * 128;          // probe words (6 used, 64B spread)
        int* pmb = flags + 2048 + cl * 128;   // consensus masks
        st_sc0(pzb + qc * 16, MAGIC);
        u32 seen = 1u << qc;
        for (int spin = 0; spin < 768 && seen != 0x3Fu; ++spin) {
            #pragma unroll
            for (int r = 0; r < NQC; ++r)
                if (!((seen >> r) & 1u) && ld_sc0(pzb + r * 16) == MAGIC) seen |= 1u << r;
            __builtin_amdgcn_s_sleep(2);
        }
        __hip_atomic_store(pmb + qc * 16, (int)(0x100u | seen),
                           __ATOMIC_RELAXED, __HIP_MEMORY_SCOPE_AGENT);
        u32 m = 0x3Fu;
        int spin2 = 0;
        #pragma unroll
        for (int r = 0; r < NQC; ++r) {
            u32 v;
            do {
                v = (u32)__hip_atomic_load(pmb + r * 16, __ATOMIC_RELAXED,
                                           __HIP_MEMORY_SCOPE_AGENT);
            } while (!(v & 0x100u) && ++spin2 < MAX_RETRY);
            m &= v;
        }
        s_fast = ((m & 0x3Fu) == 0x3Fu && spin2 < MAX_RETRY) ? 1 : 0;
    }
    __syncthreads();
    const bool fast = (s_fast != 0);

    const u16* xgd = xg + (size_t)d * NB * S2 * NG;

    // ci preload into a NAMED register buffer (16 asm ushort loads, constant count)
    u32 crA[4][4], crB[4][4];
    #define ISSUE_CI(crX, it2, vldX) do {                                          \
        int s2 = d ? (NS - 1 - (it2)) : (it2);                                     \
        vldX = (s2 >= 0) && (s2 < S2);                                             \
        int s2c = min(max(s2, 0), S2 - 1);                                         \
        const u16* rp_ = xgd + ((size_t)(g * 16 + q4 * 4) * S2 + s2c) * NG         \
                        + qc * 64 + w * 16 + l15;                                  \
        _Pragma("unroll")                                                          \
        for (int r_ = 0; r_ < 4; r_++) {                                           \
            asm volatile(                                                          \
                "global_load_ushort %0, %4, off\n\t"                               \
                "global_load_ushort %1, %4, off offset:768\n\t"                    \
                "global_load_ushort %2, %4, off offset:1536\n\t"                   \
                "global_load_ushort %3, %4, off offset:2304"                       \
                : "=&v"(crX[0][r_]), "=&v"(crX[1][r_]),                            \
                  "=&v"(crX[2][r_]), "=&v"(crX[3][r_])                             \
                : "v"(rp_) : "memory");                                            \
            rp_ += (size_t)S2 * NG;                                                \
        }                                                                          \
    } while (0)

    bool vldA, vldB;
    ISSUE_CI(crA, 0, vldA);

    // one step; crR holds ci(it) (already drained), crW is preload target for it+1
    auto step_body = [&](int it, u32 (&crR)[4][4], bool vldR,
                         u32 (&crW)[4][4], bool& vldW) {
        int s = d ? (NS - 1 - it) : it;
        f32x4 acc[4];

        if (it == 0) {
            WAIT_VM(0);   // ci(0) ready
            #pragma unroll
            for (int gg = 0; gg < 4; gg++)
                #pragma unroll
                for (int r = 0; r < 4; r++)
                    acc[gg][r] = vldR ? __uint_as_float(crR[gg][r] << 16) : biasreg[gg];
            ISSUE_CI(crW, 1, vldW);
            const u16* hp = h0buf + (size_t)(d * NB + g * 16) * NH;
            #pragma unroll
            for (int j = 0; j < 12; j++) {
                int ksg = 2 * ((qc + (j >> 1)) % NQC) + (j & 1);
                bf16x8 af = *(const bf16x8*)(hp + (size_t)l15 * NH + ksg * 32 + q4 * 8);
                #pragma unroll
                for (int gg = 0; gg < 4; gg++)
                    acc[gg] = __builtin_amdgcn_mfma_f32_16x16x32_bf16(af, bfr[gg][j], acc[gg], 0, 0, 0);
            }
        } else {
            const u32 T = (u32)it;
            const u32 want = T * 16u;
            u32* xb = xch + (size_t)((T & 3u) * 8 + cl) * (NQC * 1024)
                          + (u32)(l15 * 64 + q4 * 8);
            u32* p1 = xb + ((qc + 1) % NQC) * 1024;
            u32* p2 = xb + ((qc + 2) % NQC) * 1024;
            u32* p3 = xb + ((qc + 3) % NQC) * 1024;
            u32* p4 = xb + ((qc + 4) % NQC) * 1024;
            u32* p5 = xb + ((qc + 5) % NQC) * 1024;
            u32x4 r10, r11, r12, r13, r20, r21, r22, r23, r30, r31, r32, r33;
            u32x4 r40, r41, r42, r43, r50, r51, r52, r53;
            // entering: [stores(8)|ci(it)(<=16)]; issue exch(20) THEN ci(it+1)(16)
            ld4_nw(fast, p1, r10, r11, r12, r13);
            ld4_nw(fast, p2, r20, r21, r22, r23);
            ld4_nw(fast, p3, r30, r31, r32, r33);
            ld4_nw(fast, p4, r40, r41, r42, r43);
            ld4_nw(fast, p5, r50, r51, r52, r53);
            ISSUE_CI(crW, it + 1, vldW);
            WAIT_VM(36);   // drains stores+ci(it) (in flight a full step -> free)
            #pragma unroll
            for (int gg = 0; gg < 4; gg++)
                #pragma unroll
                for (int r = 0; r < 4; r++)
                    acc[gg][r] = vldR ? __uint_as_float(crR[gg][r] << 16) : biasreg[gg];
            // own chunk from double-buffered LDS (written by cell of step it-1)
            {
                const u16* hb = &hlds[(it - 1) & 1][0];
                bf16x8 afo0 = *(const bf16x8*)&hb[l15 * 72 + q4 * 8];
                bf16x8 afo1 = *(const bf16x8*)&hb[l15 * 72 + 32 + q4 * 8];
                #pragma unroll
                for (int gg = 0; gg < 4; gg++)
                    acc[gg] = __builtin_amdgcn_mfma_f32_16x16x32_bf16(afo0, bfr[gg][0], acc[gg], 0, 0, 0);
                #pragma unroll
                for (int gg = 0; gg < 4; gg++)
                    acc[gg] = __builtin_amdgcn_mfma_f32_16x16x32_bf16(afo1, bfr[gg][1], acc[gg], 0, 0, 0);
            }
            int tries;
            // chunk 1 (oldest exch; ci(it+1) is NEWER -> untouched)
            WAIT_VM(32);
            tries = 0;
            while (!__all(sum4(r10, r11, r12, r13) == want) && ++tries < MAX_RETRY)
                ld4_wt(fast, p1, r10, r11, r12, r13);
            {
                bf16x8 lo = packf(r10, r11), hi = packf(r12, r13);
                #pragma unroll
                for (int gg = 0; gg < 4; gg++)
                    acc[gg] = __builtin_amdgcn_mfma_f32_16x16x32_bf16(lo, bfr[gg][2], acc[gg], 0, 0, 0);
                #pragma unroll
                for (int gg = 0; gg < 4; gg++)
                    acc[gg] = __builtin_amdgcn_mfma_f32_16x16x32_bf16(hi, bfr[gg][3], acc[gg], 0, 0, 0);
            }
            // chunk 2
            WAIT_VM(28);
            tries = 0;
            while (!__all(sum4(r20, r21, r22, r23) == want) && ++tries < MAX_RETRY)
                ld4_wt(fast, p2, r20, r21, r22, r23);
            {
                bf16x8 lo = packf(r20, r21), hi = packf(r22, r23);
                #pragma unroll
                for (int gg = 0; gg < 4; gg++)
                    acc[gg] = __builtin_amdgcn_mfma_f32_16x16x32_bf16(lo, bfr[gg][4], acc[gg], 0, 0, 0);
                #pragma unroll
                for (int gg = 0; gg < 4; gg++)
                    acc[gg] = __builtin_amdgcn_mfma_f32_16x16x32_bf16(hi, bfr[gg][5], acc[gg], 0, 0, 0);
            }
            // chunk 3
            WAIT_VM(24);
            tries = 0;
            while (!__all(sum4(r30, r31, r32, r33) == want) && ++tries < MAX_RETRY)
                ld4_wt(fast, p3, r30, r31, r32, r33);
            {
                bf16x8 lo = packf(r30, r31), hi = packf(r32, r33);
                #pragma unroll
                for (int gg = 0; gg < 4; gg++)
                    acc[gg] = __builtin_amdgcn_mfma_f32_16x16x32_bf16(lo, bfr[gg][6], acc[gg], 0, 0, 0);
                #pragma unroll
                for (int gg = 0; gg < 4; gg++)
                    acc[gg] = __builtin_amdgcn_mfma_f32_16x16x32_bf16(hi, bfr[gg][7], acc[gg], 0, 0, 0);
            }
            // chunk 4
            WAIT_VM(20);
            tries = 0;
            while (!__all(sum4(r40, r41, r42, r43) == want) && ++tries < MAX_RETRY)
                ld4_wt(fast, p4, r40, r41, r42, r43);
            {
                bf16x8 lo = packf(r40, r41), hi = packf(r42, r43);
                #pragma unroll
                for (int gg = 0; gg < 4; gg++)
                    acc[gg] = __builtin_amdgcn_mfma_f32_16x16x32_bf16(lo, bfr[gg][8], acc[gg], 0, 0, 0);
                #pragma unroll
                for (int gg = 0; gg < 4; gg++)
                    acc[gg] = __builtin_amdgcn_mfma_f32_16x16x32_bf16(hi, bfr[gg][9], acc[gg], 0, 0, 0);
            }
            // chunk 5
            WAIT_VM(16);
            tries = 0;
            while (!__all(sum4(r50, r51, r52, r53) == want) && ++tries < MAX_RETRY)
                ld4_wt(fast, p5, r50, r51, r52, r53);
            {
                bf16x8 lo = packf(r50, r51), hi = packf(r52, r53);
                #pragma unroll
                for (int gg = 0; gg < 4; gg++)
                    acc[gg] = __builtin_amdgcn_mfma_f32_16x16x32_bf16(lo, bfr[gg][10], acc[gg], 0, 0, 0);
                #pragma unroll
                for (int gg = 0; gg < 4; gg++)
                    acc[gg] = __builtin_amdgcn_mfma_f32_16x16x32_bf16(hi, bfr[gg][11], acc[gg], 0, 0, 0);
            }
        }

        // cell update: fully register-local (acc[gate][r] = i,f,g,o of same (b,j))
        {
            u32 t2 = (u32)it + 1u;
            u16 hv[4];
            #pragma unroll
            for (int r = 0; r < 4; r++) {
                float gi = acc[0][r], gf = acc[1][r];
                float gz = acc[2][r], go = acc[3][r];
                float c = cre[r];
                float cn = sigm(gf) * c + sigm(gi) * tanh_(gz);
                float hn = sigm(go) * tanh_(cn);
                cre[r] = cn;
                hv[r] = f2b(hn);
            }
            u32 tg0 = ((u32)hv[0] << 16) | t2, tg1 = ((u32)hv[1] << 16) | t2;
            u32 tg2 = ((u32)hv[2] << 16) | t2, tg3 = ((u32)hv[3] << 16) | t2;
            // tagged publish FIRST: 4 dwords at batch stride 64 words (256 B)
            u32* xp = xch + (size_t)((t2 & 3u) * 8 + cl) * (NQC * 1024)
                          + (u32)(qc * 1024 + (q4 * 4) * 64 + w * 16 + l15);
            if (fast)
                asm volatile(
                    "global_store_dword %0, %1, off sc0\n\t"
                    "global_store_dword %0, %2, off offset:256 sc0\n\t"
                    "global_store_dword %0, %3, off offset:512 sc0\n\t"
                    "global_store_dword %0, %4, off offset:768 sc0"
                    :: "v"(xp), "v"(tg0), "v"(tg1), "v"(tg2), "v"(tg3) : "memory");
            else {
                __hip_atomic_store(xp,       tg0, __ATOMIC_RELAXED, __HIP_MEMORY_SCOPE_AGENT);
                __hip_atomic_store(xp + 64,  tg1, __ATOMIC_RELAXED, __HIP_MEMORY_SCOPE_AGENT);
                __hip_atomic_store(xp + 128, tg2, __ATOMIC_RELAXED, __HIP_MEMORY_SCOPE_AGENT);
                __hip_atomic_store(xp + 192, tg3, __ATOMIC_RELAXED, __HIP_MEMORY_SCOPE_AGENT);
            }
            // output history (plain cached, batch-strided)
            size_t hob = ((size_t)(d * NB + g * 16 + q4 * 4) * NS + s) * NH
                         + qc * 64 + w * 16 + l15;
            hout[hob] = hv[0];
            hout[hob + (size_t)NS * NH] = hv[1];
            hout[hob + (size_t)2 * NS * NH] = hv[2];
            hout[hob + (size_t)3 * NS * NH] = hv[3];
            // own chunk -> double-buffered LDS for next step
            u16* hb = &hlds[it & 1][0];
            hb[(q4 * 4 + 0) * 72 + w * 16 + l15] = hv[0];
            hb[(q4 * 4 + 1) * 72 + w * 16 + l15] = hv[1];
            hb[(q4 * 4 + 2) * 72 + w * 16 + l15] = hv[2];
            hb[(q4 * 4 + 3) * 72 + w * 16 + l15] = hv[3];
        }
        ldsbar();   // the ONLY barrier per step (lgkm-only)
    };

    #pragma unroll 1
    for (int itp = 0; itp < NS; itp += 2) {
        step_body(itp,     crA, vldA, crB, vldB);
        step_body(itp + 1, crB, vldB, crA, vldA);
    }
    #undef ISSUE_CI
}

// ---------------- final linear: out[b,t,22] = [hf|hb] @ WlinT + blin ----------------
__global__ void k_final(const u16* __restrict__ hout, const float* __restrict__ wlin,
                        const float* __restrict__ blin, float* __restrict__ out) {
    int r = blockIdx.x * 256 + threadIdx.x;   // 0..32767
    int b = r >> 9, t = r & 511;
    const u16* hf = hout + ((size_t)b * NS + t) * NH;
    const u16* hb = hout + ((size_t)(NB + b) * NS + t) * NH;
    float acc[NT_OUT];
    #pragma unroll
    for (int tt = 0; tt < NT_OUT; tt++) acc[tt] = blin[tt];
    #pragma unroll 1
    for (int half = 0; half < 2; half++) {
        const u16* hp = half ? hb : hf;
        #pragma unroll 1
        for (int k8 = 0; k8 < NH / 8; k8++) {
            uint4 pk = *(const uint4*)(hp + k8 * 8);
            float x[8];
            x[0] = __uint_as_float(pk.x << 16); x[1] = __uint_as_float(pk.x & 0xffff0000u);
            x[2] = __uint_as_float(pk.y << 16); x[3] = __uint_as_float(pk.y & 0xffff0000u);
            x[4] = __uint_as_float(pk.z << 16); x[5] = __uint_as_float(pk.z & 0xffff0000u);
            x[6] = __uint_as_float(pk.w << 16); x[7] = __uint_as_float(pk.w & 0xffff0000u);
            int kk = half * NH + k8 * 8;
            #pragma unroll
            for (int e = 0; e < 8; e++)
                #pragma unroll
                for (int tt = 0; tt < NT_OUT; tt++)
                    acc[tt] += x[e] * wlin[tt * (2 * NH) + kk + e];   // uniform -> s_load
        }
    }
    float* op = out + (size_t)r * NT_OUT;
    #pragma unroll
    for (int tt = 0; tt < NT_OUT; tt++) op[tt] = acc[tt];
}

extern "C" void kernel_launch(void* const* d_in, const int* in_sizes, int n_in,
                              void* d_out, int out_size, void* d_ws, size_t ws_size,
                              hipStream_t stream) {
    const float* hidden = (const float*)d_in[0];
    const float* h0     = (const float*)d_in[1];
    const float* c0     = (const float*)d_in[2];
    const float* Wihf   = (const float*)d_in[3];
    const float* Whhf   = (const float*)d_in[4];
    const float* bihf   = (const float*)d_in[5];
    const float* bhhf   = (const float*)d_in[6];
    const float* Wihb   = (const float*)d_in[7];
    const float* Whhb   = (const float*)d_in[8];
    const float* bihb   = (const float*)d_in[9];
    const float* bhhb   = (const float*)d_in[10];
    const float* Wlin   = (const float*)d_in[11];
    const float* blin   = (const float*)d_in[12];
    const int* start_ids = (const int*)d_in[13];
    const int* masks     = (const int*)d_in[14];
    float* out = (float*)d_out;

    char* ws = (char*)d_ws;
    size_t off = 0;
    auto alloc = [&](size_t bytes) { void* p = ws + off; off += (bytes + 255) & ~(size_t)255; return p; };
    u16* embeds   = (u16*)alloc((size_t)MGEMM * ND * 2);           // 26.7 MB
    u16* wihcat   = (u16*)alloc((size_t)2 * NG * ND * 2);          // 4.7 MB
    float* biascat = (float*)alloc((size_t)2 * NG * 4);            // 12 KB
    u16* whhpack  = (u16*)alloc((size_t)2 * NG * NH * 2);          // 2.36 MB
    u16* h0buf    = (u16*)alloc((size_t)2 * NB * NH * 2);          // 98 KB
    u16* xg       = (u16*)alloc((size_t)2 * NB * S2 * NG * 2);     // 107 MB
    u16* hout     = (u16*)alloc((size_t)2 * NB * NS * NH * 2);     // 50.3 MB
    int* flags    = (int*)alloc((size_t)8 * NS * 4);               // 16 KB (probe+consensus)
    u32* xch      = (u32*)alloc((size_t)4 * 8 * NQC * 1024 * 4);   // 786 KB tagged h exchange

    (void)hipMemsetAsync(flags, 0, (size_t)8 * NS * 4, stream);
    (void)hipMemsetAsync(xch, 0, (size_t)4 * 8 * NQC * 1024 * 4, stream);
    k_prep<<<256, 256, 0, stream>>>(hidden, start_ids, masks, embeds);
    k_weights<<<512, 256, 0, stream>>>(Wihf, Wihb, bihf, bhhf, bihb, bhhb, h0,
                                       wihcat, biascat, h0buf);
    k_packwhh<<<576, 256, 0, stream>>>(Whhf, Whhb, whhpack);
    dim3 ggrid(2 * NG / 128, MGEMM / 128);
    k_gemm<<<ggrid, 256, 0, stream>>>(embeds, wihcat, biascat, xg);
    k_recur<<<48, 256, 0, stream>>>(whhpack, xg, biascat, h0buf, c0, hout, flags, xch);
    k_final<<<128, 256, 0, stream>>>(hout, Wlin, blin, out);
}

// Round 13
// 2567.667 us; speedup vs baseline: 1.0771x; 1.0771x over previous
//
#include <hip/hip_runtime.h>

typedef unsigned short u16;
typedef unsigned int u32;
typedef unsigned long long u64;

typedef short bf16x8 __attribute__((ext_vector_type(8)));
typedef float f32x4 __attribute__((ext_vector_type(4)));
typedef u32 u32x4 __attribute__((ext_vector_type(4)));

#define NB 64
#define NS 512
#define ND 768
#define NH 384
#define NT_OUT 22
#define S2 272           // materialized xg time extent (n[b] <= 256 < 272)
#define NG 1536          // 4*H
#define MGEMM (NB*S2)    // 17408
#define MAGIC 0x5A5AA5A5u
#define MAX_RETRY 1000000  // watchdog: visibility failure -> wrong answer, never a hang
#define NQC 6              // j-chunks per cluster (64 j each)

__device__ __forceinline__ u16 f2b(float f) {
    u32 u = __float_as_uint(f);
    u32 r = (u + 0x7fffu + ((u >> 16) & 1u)) >> 16;
    return (u16)r;
}
__device__ __forceinline__ float b2f(u16 s) { return __uint_as_float(((u32)s) << 16); }

__device__ __forceinline__ float sigm(float x) {
    return __builtin_amdgcn_rcpf(1.f + __expf(-x));
}
__device__ __forceinline__ float tanh_(float x) {
    return 1.f - 2.f * __builtin_amdgcn_rcpf(1.f + __expf(2.f * x));
}

__device__ __forceinline__ void gl_lds16(const void* g, void* l) {
    __builtin_amdgcn_global_load_lds(
        (const __attribute__((address_space(1))) unsigned int*)g,
        (__attribute__((address_space(3))) unsigned int*)l, 16, 0, 0);
}

// ---------------- exchange access helpers ----------------
// HW LESSON (R2 vs R4 A/B): plain global_load with sc0/sc1 can hit a STALE L1 line
// on gfx950. `nt` (no L1 allocate) makes re-loads observe fresh L2 data.
// vmcnt LESSON (R9/R12): vmcnt completes IN ORDER; retry loads are the NEWEST ops
// and are only guaranteed complete at vmcnt(0) -> polls must run with an L2-only
// queue; L3 ci loads are issued AFTER the last poll (R11 ordering — proven best).
__device__ __forceinline__ u32 ld_sc0(const int* p) {
    u32 v;
    asm volatile("global_load_dword %0, %1, off sc0 nt\n\t"
                 "s_waitcnt vmcnt(0)"
                 : "=&v"(v) : "v"(p) : "memory");
    return v;
}
__device__ __forceinline__ void st_sc0(int* p, u32 v) {
    asm volatile("global_store_dword %0, %1, off sc0" :: "v"(p), "v"(v) : "memory");
}

// one chunk (64 j = 2 k-slices): 4x dwordx4 of tagged words, no wait
__device__ __forceinline__ void ld4_fast_nw(const u32* p,
        u32x4& A, u32x4& B, u32x4& C, u32x4& D) {
    asm volatile(
        "global_load_dwordx4 %0, %4, off sc0 nt\n\t"
        "global_load_dwordx4 %1, %4, off offset:16 sc0 nt\n\t"
        "global_load_dwordx4 %2, %4, off offset:128 sc0 nt\n\t"
        "global_load_dwordx4 %3, %4, off offset:144 sc0 nt"
        : "=&v"(A), "=&v"(B), "=&v"(C), "=&v"(D)
        : "v"(p) : "memory");
}
__device__ __forceinline__ void ld4_fast_wt(const u32* p,
        u32x4& A, u32x4& B, u32x4& C, u32x4& D) {
    asm volatile(
        "global_load_dwordx4 %0, %4, off sc0 nt\n\t"
        "global_load_dwordx4 %1, %4, off offset:16 sc0 nt\n\t"
        "global_load_dwordx4 %2, %4, off offset:128 sc0 nt\n\t"
        "global_load_dwordx4 %3, %4, off offset:144 sc0 nt\n\t"
        "s_waitcnt vmcnt(0)"
        : "=&v"(A), "=&v"(B), "=&v"(C), "=&v"(D)
        : "v"(p) : "memory");
}
__device__ __forceinline__ void ld4_slow(const u32* p,
        u32x4& A, u32x4& B, u32x4& C, u32x4& D) {
    #pragma unroll
    for (int e = 0; e < 4; e++) {
        A[e] = __hip_atomic_load(p + e,      __ATOMIC_RELAXED, __HIP_MEMORY_SCOPE_AGENT);
        B[e] = __hip_atomic_load(p + 4 + e,  __ATOMIC_RELAXED, __HIP_MEMORY_SCOPE_AGENT);
        C[e] = __hip_atomic_load(p + 32 + e, __ATOMIC_RELAXED, __HIP_MEMORY_SCOPE_AGENT);
        D[e] = __hip_atomic_load(p + 36 + e, __ATOMIC_RELAXED, __HIP_MEMORY_SCOPE_AGENT);
    }
}
__device__ __forceinline__ void ld4_nw(bool fast, const u32* p,
        u32x4& A, u32x4& B, u32x4& C, u32x4& D) {
    if (fast) ld4_fast_nw(p, A, B, C, D);
    else      ld4_slow(p, A, B, C, D);
}
__device__ __forceinline__ void ld4_wt(bool fast, const u32* p,
        u32x4& A, u32x4& B, u32x4& C, u32x4& D) {
    if (fast) ld4_fast_wt(p, A, B, C, D);
    else      ld4_slow(p, A, B, C, D);
}
#define WAIT_VM(N) do { __builtin_amdgcn_sched_barrier(0); \
    asm volatile("s_waitcnt vmcnt(" #N ")" ::: "memory"); \
    __builtin_amdgcn_sched_barrier(0); } while (0)
// LDS-only barrier (global exchange is self-validating; no vm drain)
__device__ __forceinline__ void ldsbar() {
    asm volatile("s_waitcnt lgkmcnt(0)" ::: "memory");
    __builtin_amdgcn_s_barrier();
    __builtin_amdgcn_sched_barrier(0);
}

// sum of low-16 tags of 16 words; tags monotone (stale in {0, T-4}) so
// sum == 16*T  <=>  all 16 words carry tag T.
__device__ __forceinline__ u32 sum4(const u32x4& a, const u32x4& b,
                                    const u32x4& c, const u32x4& d) {
    u32 s = (a[0] & 0xffffu) + (a[1] & 0xffffu) + (a[2] & 0xffffu) + (a[3] & 0xffffu);
    s += (b[0] & 0xffffu) + (b[1] & 0xffffu) + (b[2] & 0xffffu) + (b[3] & 0xffffu);
    s += (c[0] & 0xffffu) + (c[1] & 0xffffu) + (c[2] & 0xffffu) + (c[3] & 0xffffu);
    s += (d[0] & 0xffffu) + (d[1] & 0xffffu) + (d[2] & 0xffffu) + (d[3] & 0xffffu);
    return s;
}
// pack 8 tagged words (h in high 16 bits) -> bf16x8 fragment
__device__ __forceinline__ bf16x8 packf(const u32x4& lo, const u32x4& hi) {
    union { u32 q[4]; bf16x8 v; } U;
    U.q[0] = __builtin_amdgcn_perm(lo[1], lo[0], 0x07060302u);
    U.q[1] = __builtin_amdgcn_perm(lo[3], lo[2], 0x07060302u);
    U.q[2] = __builtin_amdgcn_perm(hi[1], hi[0], 0x07060302u);
    U.q[3] = __builtin_amdgcn_perm(hi[3], hi[2], 0x07060302u);
    return U.v;
}

// ---------------- prep: align/gather -> embeds bf16 [64][272][768] ----------------
__global__ void k_prep(const float* __restrict__ hidden, const int* __restrict__ start_ids,
                       const int* __restrict__ masks, u16* __restrict__ embeds) {
    int b = blockIdx.x >> 2;
    int quarter = blockIdx.x & 3;
    int tid = threadIdx.x;
    __shared__ int red[256];
    int cn = 0, cm = 0;
    for (int s = tid; s < NS; s += 256) {
        cn += (start_ids[b * NS + s] >= 0) ? 1 : 0;
        cm += (masks[b * NS + s] != 0) ? 1 : 0;
    }
    red[tid] = cn + (cm << 16);
    __syncthreads();
    #pragma unroll
    for (int off = 128; off > 0; off >>= 1) {
        if (tid < off) red[tid] += red[tid + off];
        __syncthreads();
    }
    int n = red[0] & 0xffff;
    int slen = red[0] >> 16;
    n = min(max(n, 1), NS);
    int last = start_ids[b * NS + n - 1];
    for (int t = quarter * 68; t < quarter * 68 + 68; ++t) {
        int idx;
        if (t == 0) idx = 0;
        else if (t < n) idx = start_ids[b * NS + t] - 1;
        else if (t == n) idx = last;
        else idx = 0;
        idx = min(max(idx, 0), NS - 1);
        bool keep = t < slen;
        const float* src = hidden + ((size_t)b * NS + idx) * ND;
        u16* dst = embeds + ((size_t)b * S2 + t) * ND;
        if (tid < 192) {
            float4 v = keep ? *(const float4*)(src + tid * 4) : make_float4(0.f, 0.f, 0.f, 0.f);
            union { u16 u[4]; uint2 q; } pk;
            pk.u[0] = f2b(v.x); pk.u[1] = f2b(v.y); pk.u[2] = f2b(v.z); pk.u[3] = f2b(v.w);
            *(uint2*)(dst + tid * 4) = pk.q;
        }
    }
}

// ---------------- weights: cast W_ih (cat) to bf16, bias sums, h0 cast ----------------
__global__ void k_weights(const float* __restrict__ wf, const float* __restrict__ wb,
                          const float* __restrict__ bihf, const float* __restrict__ bhhf,
                          const float* __restrict__ bihb, const float* __restrict__ bhhb,
                          const float* __restrict__ h0,
                          u16* __restrict__ wihcat, float* __restrict__ biascat,
                          u16* __restrict__ h0buf) {
    int i0 = blockIdx.x * blockDim.x + threadIdx.x;
    int NTH = gridDim.x * blockDim.x;
    for (size_t i = i0; i < (size_t)2 * NG * ND; i += NTH) {
        size_t nrow = i / ND, k = i - nrow * ND;
        float v = (nrow < NG) ? wf[nrow * ND + k] : wb[(nrow - NG) * ND + k];
        wihcat[i] = f2b(v);
    }
    for (int i = i0; i < 2 * NG; i += NTH)
        biascat[i] = (i < NG) ? bihf[i] + bhhf[i] : bihb[i - NG] + bhhb[i - NG];
    for (int i = i0; i < 2 * NB * NH; i += NTH) h0buf[i] = f2b(h0[i]);
}

// ---------------- pack Whh into MFMA B-fragment order (GATE-LOCAL) ----------------
// layout: [d][qc6][wj4][gate4][ks12][lane][8]
// (qc: 64-j chunk; wj: wave's 16-j tile; gate-local -> cell is register-local)
__global__ void k_packwhh(const float* __restrict__ whhf, const float* __restrict__ whhb,
                          u16* __restrict__ pack) {
    int ft = blockIdx.x * 256 + threadIdx.x;
    if (ft >= 2 * NQC * 4 * 4 * 12 * 64) return;
    int lane = ft & 63;
    int grp = ft >> 6;
    int ks = grp % 12; grp /= 12;
    int gate = grp & 3; grp >>= 2;
    int wj = grp & 3;  grp >>= 2;
    int qc = grp % NQC;
    int d  = grp / NQC;
    const float* W = d ? whhb : whhf;
    int col = gate * NH + qc * 64 + wj * 16 + (lane & 15);
    int k0 = ks * 32 + (lane >> 4) * 8;
    u16* dst = pack + (size_t)ft * 8;
    #pragma unroll
    for (int e = 0; e < 8; e++) dst[e] = f2b(W[(size_t)col * NH + k0 + e]);
}

// ---------------- GEMM: xg[d][b][t<272][1536] (bf16) = embeds @ WihcatT + bias ----------------
__launch_bounds__(256, 2)
__global__ void k_gemm(const u16* __restrict__ A, const u16* __restrict__ Bw,
                       const float* __restrict__ biascat, u16* __restrict__ xg) {
    __shared__ u16 As[128 * 32];
    __shared__ u16 Bs[128 * 32];
    int tid = threadIdx.x;
    int lane = tid & 63, wid = tid >> 6;
    int l15 = lane & 15, q4 = lane >> 4;
    int bn = blockIdx.x;   // 24 tiles of N=3072
    int bm = blockIdx.y;   // 136 tiles of M=17408
    int wm = (wid >> 1) * 64, wn = (wid & 1) * 64;
    f32x4 acc[4][4] = {};
    for (int k0 = 0; k0 < ND; k0 += 32) {
        #pragma unroll
        for (int j = 0; j < 2; j++) {
            int fl = tid + j * 256;
            int row = fl >> 2, cb = fl & 3;
            const u16* ga = A + (size_t)(bm * 128 + row) * ND + k0 + cb * 8;
            gl_lds16(ga, &As[(size_t)(wid * 64 + j * 256) * 8]);
            const u16* gb = Bw + (size_t)(bn * 128 + row) * ND + k0 + cb * 8;
            gl_lds16(gb, &Bs[(size_t)(wid * 64 + j * 256) * 8]);
        }
        __syncthreads();
        bf16x8 af[4], bf[4];
        #pragma unroll
        for (int mt = 0; mt < 4; mt++)
            af[mt] = *(const bf16x8*)&As[(wm + mt * 16 + l15) * 32 + q4 * 8];
        #pragma unroll
        for (int nt = 0; nt < 4; nt++)
            bf[nt] = *(const bf16x8*)&Bs[(wn + nt * 16 + l15) * 32 + q4 * 8];
        #pragma unroll
        for (int mt = 0; mt < 4; mt++)
            #pragma unroll
            for (int nt = 0; nt < 4; nt++)
                acc[mt][nt] = __builtin_amdgcn_mfma_f32_16x16x32_bf16(af[mt], bf[nt], acc[mt][nt], 0, 0, 0);
        __syncthreads();
    }
    #pragma unroll
    for (int nt = 0; nt < 4; nt++) {
        int gn = bn * 128 + wn + nt * 16 + l15;
        int d = gn >= NG ? 1 : 0;
        int col = gn - d * NG;
        float bias = biascat[gn];
        #pragma unroll
        for (int mt = 0; mt < 4; mt++) {
            #pragma unroll
            for (int r = 0; r < 4; r++) {
                int m = bm * 128 + wm + mt * 16 + q4 * 4 + r;
                int b = m / S2, t = m - b * S2;
                float v = acc[mt][nt][r] + bias;
                xg[((size_t)(d * NB + b) * S2 + t) * NG + col] = f2b(v);
            }
        }
    }
}

// ---------------- recurrence: 6-WG gate-local, register-local cell, 1 barrier ----------------
// 48 WGs; cluster = (dir, batch-group) of SIX 64-j WGs (blk%8 -> same-XCD heuristic).
// R13 = R11 verbatim (proven best: k_recur 2037us, total 2568us). All pipelining
// variants around this configuration (R6/R7/R8/R12) regressed for understood
// mechanical reasons (stale-L1 polls, in-order vmcnt vs retries, L2 own-chunk).
//  - 6-WG/64j: 48 MFMA/wave, 48 CUs.
//  - GATE-LOCAL waves: acc[gate][r] holds i,f,g,o of the same (batch,j) -> cell is
//    pure register math, NO preact LDS, 4 elems/thread.
//  - own chunk in DOUBLE-BUFFERED LDS + ONE lgkm barrier/step.
//  - vmcnt discipline: 20 exch loads up-front, counted polls 16/12/8/4/0, retries
//    via vmcnt(0) on an L2-only queue, 16 asm-ci loads issued AFTER the last poll,
//    drained by next step's WAIT(20).
__launch_bounds__(256, 1)
__global__ void k_recur(const u16* __restrict__ whhpack, const u16* __restrict__ xg,
                        const float* __restrict__ biascat, const u16* __restrict__ h0buf,
                        const float* __restrict__ c0, u16* __restrict__ hout,
                        int* __restrict__ flags, u32* __restrict__ xch) {
    const int blk = blockIdx.x;      // 0..47
    const int qc = blk >> 3;         // j-chunk 0..5
    const int cl = blk & 7;          // cluster id
    const int d = cl >> 2;           // direction
    const int g = cl & 3;            // batch group (16 batches)
    const int tid = threadIdx.x, lane = tid & 63, w = tid >> 6;  // w = 16-j tile
    const int q4 = lane >> 4, l15 = lane & 15;

    __shared__ u16 hlds[2][16 * 72];   // own 64-j chunk, double-buffered, pad 72
    __shared__ int s_fast;

    // stationary Whh B-fragments: bfr[gate][j], j=2i+(0|1) = (lo|hi) 32-k slice of
    // chunk (qc+i)%6 (i=0 own).
    bf16x8 bfr[4][12];
    #pragma unroll
    for (int gg = 0; gg < 4; gg++)
        #pragma unroll
        for (int j = 0; j < 12; j++) {
            int ksg = 2 * ((qc + (j >> 1)) % NQC) + (j & 1);
            bfr[gg][j] = *(const bf16x8*)(whhpack +
                ((size_t)((((d * NQC + qc) * 4 + w) * 4 + gg) * 12 + ksg) * 64 + lane) * 8);
        }

    // c-state: thread owns (batch=q4*4+r, j=w*16+l15), r=0..3
    float cre[4];
    #pragma unroll
    for (int r = 0; r < 4; r++)
        cre[r] = c0[(size_t)(d * NB + g * 16 + q4 * 4 + r) * NH + qc * 64 + w * 16 + l15];
    float biasreg[4];
    #pragma unroll
    for (int gg = 0; gg < 4; gg++)
        biasreg[gg] = biascat[d * NG + gg * NH + qc * 64 + w * 16 + l15];

    // ---- co-location probe + consensus (once per launch) ----
    if (tid == 0) {
        int* pzb = flags + cl * 128;          // probe words (6 used, 64B spread)
        int* pmb = flags + 2048 + cl * 128;   // consensus masks
        st_sc0(pzb + qc * 16, MAGIC);
        u32 seen = 1u << qc;
        for (int spin = 0; spin < 768 && seen != 0x3Fu; ++spin) {
            #pragma unroll
            for (int r = 0; r < NQC; ++r)
                if (!((seen >> r) & 1u) && ld_sc0(pzb + r * 16) == MAGIC) seen |= 1u << r;
            __builtin_amdgcn_s_sleep(2);
        }
        __hip_atomic_store(pmb + qc * 16, (int)(0x100u | seen),
                           __ATOMIC_RELAXED, __HIP_MEMORY_SCOPE_AGENT);
        u32 m = 0x3Fu;
        int spin2 = 0;
        #pragma unroll
        for (int r = 0; r < NQC; ++r) {
            u32 v;
            do {
                v = (u32)__hip_atomic_load(pmb + r * 16, __ATOMIC_RELAXED,
                                           __HIP_MEMORY_SCOPE_AGENT);
            } while (!(v & 0x100u) && ++spin2 < MAX_RETRY);
            m &= v;
        }
        s_fast = ((m & 0x3Fu) == 0x3Fu && spin2 < MAX_RETRY) ? 1 : 0;
    }
    __syncthreads();
    const bool fast = (s_fast != 0);

    const u16* xgd = xg + (size_t)d * NB * S2 * NG;

    // ci preload: 16 asm ushort loads (4 gates x 4 batch-rows), counted in the
    // vmcnt ledger. Always issues (clamped row) so the ledger is constant.
    u32 cr[4][4];
    auto issue_preload = [&](int it2) -> bool {
        int s2 = d ? (NS - 1 - it2) : it2;
        bool ok = (s2 >= 0) && (s2 < S2);
        int s2c = min(max(s2, 0), S2 - 1);
        const u16* rp = xgd + ((size_t)(g * 16 + q4 * 4) * S2 + s2c) * NG
                        + qc * 64 + w * 16 + l15;
        #pragma unroll
        for (int r = 0; r < 4; r++) {
            asm volatile(
                "global_load_ushort %0, %4, off\n\t"
                "global_load_ushort %1, %4, off offset:768\n\t"
                "global_load_ushort %2, %4, off offset:1536\n\t"
                "global_load_ushort %3, %4, off offset:2304"
                : "=&v"(cr[0][r]), "=&v"(cr[1][r]), "=&v"(cr[2][r]), "=&v"(cr[3][r])
                : "v"(rp) : "memory");
            rp += (size_t)S2 * NG;
        }
        return ok;
    };
    bool vld = issue_preload(0);

    #pragma unroll 1
    for (int it = 0; it < NS; ++it) {
        int s = d ? (NS - 1 - it) : it;
        f32x4 acc[4];

        if (it == 0) {
            WAIT_VM(0);   // ci(0) ready
            #pragma unroll
            for (int gg = 0; gg < 4; gg++)
                #pragma unroll
                for (int r = 0; r < 4; r++)
                    acc[gg][r] = vld ? __uint_as_float(cr[gg][r] << 16) : biasreg[gg];
            vld = issue_preload(1);
            const u16* hp = h0buf + (size_t)(d * NB + g * 16) * NH;
            #pragma unroll
            for (int j = 0; j < 12; j++) {
                int ksg = 2 * ((qc + (j >> 1)) % NQC) + (j & 1);
                bf16x8 af = *(const bf16x8*)(hp + (size_t)l15 * NH + ksg * 32 + q4 * 8);
                #pragma unroll
                for (int gg = 0; gg < 4; gg++)
                    acc[gg] = __builtin_amdgcn_mfma_f32_16x16x32_bf16(af, bfr[gg][j], acc[gg], 0, 0, 0);
            }
        } else {
            const u32 T = (u32)it;
            const u32 want = T * 16u;
            u32* xb = xch + (size_t)((T & 3u) * 8 + cl) * (NQC * 1024)
                          + (u32)(l15 * 64 + q4 * 8);
            u32* p1 = xb + ((qc + 1) % NQC) * 1024;
            u32* p2 = xb + ((qc + 2) % NQC) * 1024;
            u32* p3 = xb + ((qc + 3) % NQC) * 1024;
            u32* p4 = xb + ((qc + 4) % NQC) * 1024;
            u32* p5 = xb + ((qc + 5) % NQC) * 1024;
            u32x4 r10, r11, r12, r13, r20, r21, r22, r23, r30, r31, r32, r33;
            u32x4 r40, r41, r42, r43, r50, r51, r52, r53;
            // entering: ci(16)+stores(8)=24 outstanding; issue 20 exch -> 44
            ld4_nw(fast, p1, r10, r11, r12, r13);
            ld4_nw(fast, p2, r20, r21, r22, r23);
            ld4_nw(fast, p3, r30, r31, r32, r33);
            ld4_nw(fast, p4, r40, r41, r42, r43);
            ld4_nw(fast, p5, r50, r51, r52, r53);
            WAIT_VM(20);   // drains ci+stores; leaves exactly the 20 exch loads
            #pragma unroll
            for (int gg = 0; gg < 4; gg++)
                #pragma unroll
                for (int r = 0; r < 4; r++)
                    acc[gg][r] = vld ? __uint_as_float(cr[gg][r] << 16) : biasreg[gg];
            // own chunk from double-buffered LDS (written by cell of step it-1)
            {
                const u16* hb = &hlds[(it - 1) & 1][0];
                bf16x8 afo0 = *(const bf16x8*)&hb[l15 * 72 + q4 * 8];
                bf16x8 afo1 = *(const bf16x8*)&hb[l15 * 72 + 32 + q4 * 8];
                #pragma unroll
                for (int gg = 0; gg < 4; gg++)
                    acc[gg] = __builtin_amdgcn_mfma_f32_16x16x32_bf16(afo0, bfr[gg][0], acc[gg], 0, 0, 0);
                #pragma unroll
                for (int gg = 0; gg < 4; gg++)
                    acc[gg] = __builtin_amdgcn_mfma_f32_16x16x32_bf16(afo1, bfr[gg][1], acc[gg], 0, 0, 0);
            }
            int tries;
            // chunk 1 (oldest of the 20)
            WAIT_VM(16);
            tries = 0;
            while (!__all(sum4(r10, r11, r12, r13) == want) && ++tries < MAX_RETRY)
                ld4_wt(fast, p1, r10, r11, r12, r13);   // vmcnt(0): L2-only queue
            {
                bf16x8 lo = packf(r10, r11), hi = packf(r12, r13);
                #pragma unroll
                for (int gg = 0; gg < 4; gg++)
                    acc[gg] = __builtin_amdgcn_mfma_f32_16x16x32_bf16(lo, bfr[gg][2], acc[gg], 0, 0, 0);
                #pragma unroll
                for (int gg = 0; gg < 4; gg++)
                    acc[gg] = __builtin_amdgcn_mfma_f32_16x16x32_bf16(hi, bfr[gg][3], acc[gg], 0, 0, 0);
            }
            // chunk 2
            WAIT_VM(12);
            tries = 0;
            while (!__all(sum4(r20, r21, r22, r23) == want) && ++tries < MAX_RETRY)
                ld4_wt(fast, p2, r20, r21, r22, r23);
            {
                bf16x8 lo = packf(r20, r21), hi = packf(r22, r23);
                #pragma unroll
                for (int gg = 0; gg < 4; gg++)
                    acc[gg] = __builtin_amdgcn_mfma_f32_16x16x32_bf16(lo, bfr[gg][4], acc[gg], 0, 0, 0);
                #pragma unroll
                for (int gg = 0; gg < 4; gg++)
                    acc[gg] = __builtin_amdgcn_mfma_f32_16x16x32_bf16(hi, bfr[gg][5], acc[gg], 0, 0, 0);
            }
            // chunk 3
            WAIT_VM(8);
            tries = 0;
            while (!__all(sum4(r30, r31, r32, r33) == want) && ++tries < MAX_RETRY)
                ld4_wt(fast, p3, r30, r31, r32, r33);
            {
                bf16x8 lo = packf(r30, r31), hi = packf(r32, r33);
                #pragma unroll
                for (int gg = 0; gg < 4; gg++)
                    acc[gg] = __builtin_amdgcn_mfma_f32_16x16x32_bf16(lo, bfr[gg][6], acc[gg], 0, 0, 0);
                #pragma unroll
                for (int gg = 0; gg < 4; gg++)
                    acc[gg] = __builtin_amdgcn_mfma_f32_16x16x32_bf16(hi, bfr[gg][7], acc[gg], 0, 0, 0);
            }
            // chunk 4
            WAIT_VM(4);
            tries = 0;
            while (!__all(sum4(r40, r41, r42, r43) == want) && ++tries < MAX_RETRY)
                ld4_wt(fast, p4, r40, r41, r42, r43);
            {
                bf16x8 lo = packf(r40, r41), hi = packf(r42, r43);
                #pragma unroll
                for (int gg = 0; gg < 4; gg++)
                    acc[gg] = __builtin_amdgcn_mfma_f32_16x16x32_bf16(lo, bfr[gg][8], acc[gg], 0, 0, 0);
                #pragma unroll
                for (int gg = 0; gg < 4; gg++)
                    acc[gg] = __builtin_amdgcn_mfma_f32_16x16x32_bf16(hi, bfr[gg][9], acc[gg], 0, 0, 0);
            }
            // chunk 5
            WAIT_VM(0);
            tries = 0;
            while (!__all(sum4(r50, r51, r52, r53) == want) && ++tries < MAX_RETRY)
                ld4_wt(fast, p5, r50, r51, r52, r53);
            vld = issue_preload(it + 1);   // ci AFTER polls: hides under cell+barrier
            {
                bf16x8 lo = packf(r50, r51), hi = packf(r52, r53);
                #pragma unroll
                for (int gg = 0; gg < 4; gg++)
                    acc[gg] = __builtin_amdgcn_mfma_f32_16x16x32_bf16(lo, bfr[gg][10], acc[gg], 0, 0, 0);
                #pragma unroll
                for (int gg = 0; gg < 4; gg++)
                    acc[gg] = __builtin_amdgcn_mfma_f32_16x16x32_bf16(hi, bfr[gg][11], acc[gg], 0, 0, 0);
            }
        }

        // cell update: fully register-local (acc[gate][r] = i,f,g,o of same (b,j))
        {
            u32 t2 = (u32)it + 1u;
            u16 hv[4];
            #pragma unroll
            for (int r = 0; r < 4; r++) {
                float gi = acc[0][r], gf = acc[1][r];
                float gz = acc[2][r], go = acc[3][r];
                float c = cre[r];
                float cn = sigm(gf) * c + sigm(gi) * tanh_(gz);
                float hn = sigm(go) * tanh_(cn);
                cre[r] = cn;
                hv[r] = f2b(hn);
            }
            u32 tg0 = ((u32)hv[0] << 16) | t2, tg1 = ((u32)hv[1] << 16) | t2;
            u32 tg2 = ((u32)hv[2] << 16) | t2, tg3 = ((u32)hv[3] << 16) | t2;
            // tagged publish FIRST: 4 dwords at batch stride 64 words (256 B)
            u32* xp = xch + (size_t)((t2 & 3u) * 8 + cl) * (NQC * 1024)
                          + (u32)(qc * 1024 + (q4 * 4) * 64 + w * 16 + l15);
            if (fast)
                asm volatile(
                    "global_store_dword %0, %1, off sc0\n\t"
                    "global_store_dword %0, %2, off offset:256 sc0\n\t"
                    "global_store_dword %0, %3, off offset:512 sc0\n\t"
                    "global_store_dword %0, %4, off offset:768 sc0"
                    :: "v"(xp), "v"(tg0), "v"(tg1), "v"(tg2), "v"(tg3) : "memory");
            else {
                __hip_atomic_store(xp,       tg0, __ATOMIC_RELAXED, __HIP_MEMORY_SCOPE_AGENT);
                __hip_atomic_store(xp + 64,  tg1, __ATOMIC_RELAXED, __HIP_MEMORY_SCOPE_AGENT);
                __hip_atomic_store(xp + 128, tg2, __ATOMIC_RELAXED, __HIP_MEMORY_SCOPE_AGENT);
                __hip_atomic_store(xp + 192, tg3, __ATOMIC_RELAXED, __HIP_MEMORY_SCOPE_AGENT);
            }
            // output history (plain cached, batch-strided)
            size_t hob = ((size_t)(d * NB + g * 16 + q4 * 4) * NS + s) * NH
                         + qc * 64 + w * 16 + l15;
            hout[hob] = hv[0];
            hout[hob + (size_t)NS * NH] = hv[1];
            hout[hob + (size_t)2 * NS * NH] = hv[2];
            hout[hob + (size_t)3 * NS * NH] = hv[3];
            // own chunk -> double-buffered LDS for next step
            u16* hb = &hlds[it & 1][0];
            hb[(q4 * 4 + 0) * 72 + w * 16 + l15] = hv[0];
            hb[(q4 * 4 + 1) * 72 + w * 16 + l15] = hv[1];
            hb[(q4 * 4 + 2) * 72 + w * 16 + l15] = hv[2];
            hb[(q4 * 4 + 3) * 72 + w * 16 + l15] = hv[3];
        }
        ldsbar();   // the ONLY barrier per step (lgkm-only)
    }
}

// ---------------- final linear: out[b,t,22] = [hf|hb] @ WlinT + blin ----------------
__global__ void k_final(const u16* __restrict__ hout, const float* __restrict__ wlin,
                        const float* __restrict__ blin, float* __restrict__ out) {
    int r = blockIdx.x * 256 + threadIdx.x;   // 0..32767
    int b = r >> 9, t = r & 511;
    const u16* hf = hout + ((size_t)b * NS + t) * NH;
    const u16* hb = hout + ((size_t)(NB + b) * NS + t) * NH;
    float acc[NT_OUT];
    #pragma unroll
    for (int tt = 0; tt < NT_OUT; tt++) acc[tt] = blin[tt];
    #pragma unroll 1
    for (int half = 0; half < 2; half++) {
        const u16* hp = half ? hb : hf;
        #pragma unroll 1
        for (int k8 = 0; k8 < NH / 8; k8++) {
            uint4 pk = *(const uint4*)(hp + k8 * 8);
            float x[8];
            x[0] = __uint_as_float(pk.x << 16); x[1] = __uint_as_float(pk.x & 0xffff0000u);
            x[2] = __uint_as_float(pk.y << 16); x[3] = __uint_as_float(pk.y & 0xffff0000u);
            x[4] = __uint_as_float(pk.z << 16); x[5] = __uint_as_float(pk.z & 0xffff0000u);
            x[6] = __uint_as_float(pk.w << 16); x[7] = __uint_as_float(pk.w & 0xffff0000u);
            int kk = half * NH + k8 * 8;
            #pragma unroll
            for (int e = 0; e < 8; e++)
                #pragma unroll
                for (int tt = 0; tt < NT_OUT; tt++)
                    acc[tt] += x[e] * wlin[tt * (2 * NH) + kk + e];   // uniform -> s_load
        }
    }
    float* op = out + (size_t)r * NT_OUT;
    #pragma unroll
    for (int tt = 0; tt < NT_OUT; tt++) op[tt] = acc[tt];
}

extern "C" void kernel_launch(void* const* d_in, const int* in_sizes, int n_in,
                              void* d_out, int out_size, void* d_ws, size_t ws_size,
                              hipStream_t stream) {
    const float* hidden = (const float*)d_in[0];
    const float* h0     = (const float*)d_in[1];
    const float* c0     = (const float*)d_in[2];
    const float* Wihf   = (const float*)d_in[3];
    const float* Whhf   = (const float*)d_in[4];
    const float* bihf   = (const float*)d_in[5];
    const float* bhhf   = (const float*)d_in[6];
    const float* Wihb   = (const float*)d_in[7];
    const float* Whhb   = (const float*)d_in[8];
    const float* bihb   = (const float*)d_in[9];
    const float* bhhb   = (const float*)d_in[10];
    const float* Wlin   = (const float*)d_in[11];
    const float* blin   = (const float*)d_in[12];
    const int* start_ids = (const int*)d_in[13];
    const int* masks     = (const int*)d_in[14];
    float* out = (float*)d_out;

    char* ws = (char*)d_ws;
    size_t off = 0;
    auto alloc = [&](size_t bytes) { void* p = ws + off; off += (bytes + 255) & ~(size_t)255; return p; };
    u16* embeds   = (u16*)alloc((size_t)MGEMM * ND * 2);           // 26.7 MB
    u16* wihcat   = (u16*)alloc((size_t)2 * NG * ND * 2);          // 4.7 MB
    float* biascat = (float*)alloc((size_t)2 * NG * 4);            // 12 KB
    u16* whhpack  = (u16*)alloc((size_t)2 * NG * NH * 2);          // 2.36 MB
    u16* h0buf    = (u16*)alloc((size_t)2 * NB * NH * 2);          // 98 KB
    u16* xg       = (u16*)alloc((size_t)2 * NB * S2 * NG * 2);     // 107 MB
    u16* hout     = (u16*)alloc((size_t)2 * NB * NS * NH * 2);     // 50.3 MB
    int* flags    = (int*)alloc((size_t)8 * NS * 4);               // 16 KB (probe+consensus)
    u32* xch      = (u32*)alloc((size_t)4 * 8 * NQC * 1024 * 4);   // 786 KB tagged h exchange

    (void)hipMemsetAsync(flags, 0, (size_t)8 * NS * 4, stream);
    (void)hipMemsetAsync(xch, 0, (size_t)4 * 8 * NQC * 1024 * 4, stream);
    k_prep<<<256, 256, 0, stream>>>(hidden, start_ids, masks, embeds);
    k_weights<<<512, 256, 0, stream>>>(Wihf, Wihb, bihf, bhhf, bihb, bhhb, h0,
                                       wihcat, biascat, h0buf);
    k_packwhh<<<576, 256, 0, stream>>>(Whhf, Whhb, whhpack);
    dim3 ggrid(2 * NG / 128, MGEMM / 128);
    k_gemm<<<ggrid, 256, 0, stream>>>(embeds, wihcat, biascat, xg);
    k_recur<<<48, 256, 0, stream>>>(whhpack, xg, biascat, h0buf, c0, hout, flags, xch);
    k_final<<<128, 256, 0, stream>>>(hout, Wlin, blin, out);
}